// Round 6
// baseline (20558.739 us; speedup 1.0000x reference)
//
#include <hip/hip_runtime.h>
#include <hip/hip_bf16.h>

using bf16 = __hip_bfloat16;
typedef __attribute__((ext_vector_type(8))) short bf16x8;
typedef __attribute__((ext_vector_type(4))) float f32x4;

__device__ __forceinline__ void gload16(const void* g, void* l) {
  __builtin_amdgcn_global_load_lds((const __attribute__((address_space(1))) void*)g,
                                   (__attribute__((address_space(3))) void*)l, 16, 0, 0);
}

__device__ __forceinline__ float sigm(float x) { return 1.0f / (1.0f + __expf(-x)); }
// overflow-safe fast tanh
__device__ __forceinline__ float ftanh(float x) {
  float e = __expf(2.0f * fabsf(x));
  return copysignf(1.0f - 2.0f / (e + 1.0f), x);
}

#define MFMA16(a, b, c) __builtin_amdgcn_mfma_f32_16x16x32_bf16(a, b, c, 0, 0, 0)

struct Frag { bf16x8 a0, a1, b0, b1; };

// ---------------------------------------------------------------------------
// Recurrent step GEMM: g[256,4096] = pe + a1@w1.T + a2@w2.T (+bias -bsub),
// fused LSTM-gate epilogue (weights gate-interleaved: col n = 4*h + q).
// 512 threads: wave-group 0 (waves 0-3) does a1@w1 (K=1024), group 1 a2@w2.
// K-loop: NO LDS, NO barriers — each wave loads its MFMA fragments directly
// global->VGPR (coalesced 16 rows x 64B), register-pipelined depth 6, fully
// unrolled (static frag indices). L1 absorbs the 2x cross-wave duplication;
// L2 traffic unchanged. Waves run completely decoupled until the epilogue.
// grid 256 linear (XCD-decoded), block 512.
// ---------------------------------------------------------------------------
__global__ __launch_bounds__(512) void rnn_step(
    const bf16* __restrict__ a1, const bf16* __restrict__ a2,
    const bf16* __restrict__ w1, const bf16* __restrict__ w2,
    const float* __restrict__ pe, const float* __restrict__ bias,
    const float* __restrict__ bsub,
    const float* __restrict__ c_in, float* __restrict__ c_out,
    bf16* __restrict__ h_out)
{
  __shared__ __attribute__((aligned(128))) float gs[2 * 64 * 68];  // 34KB
  const int tid = threadIdx.x;
  const int wv = tid >> 6, ln = tid & 63;
  const int grp = wv >> 2, wg = wv & 3;
  // XCD-aware decode: blocks sharing a B-panel (same nt) land on one XCD.
  const int bid = blockIdx.x;
  const int nt = ((bid & 7) << 3) | ((bid >> 3) & 7);
  const int mt = bid >> 6;
  const int m0 = mt << 6, n0 = nt << 6;
  const int wm = (wg >> 1) << 5, wn = (wg & 1) << 5;
  const bool use2 = (a2 != nullptr);

  const bf16* asrc = (grp == 0) ? a1 : (use2 ? a2 : a1);
  const bf16* wsrc = (grp == 0) ? w1 : (use2 ? w2 : w1);

  // per-lane fragment base addresses (mfma_16x16x32 operand layout:
  // lane l -> row (l&15), k-chunk (l>>4) of 8 bf16 = 16B)
  const int kc = ln >> 4, r15 = ln & 15;
  const char* pa0 = (const char*)asrc + ((size_t)(m0 + wm + r15) << 11) + (kc << 4);
  const char* pa1 = pa0 + (16 << 11);
  const char* pb0 = (const char*)wsrc + ((size_t)(n0 + wn + r15) << 11) + (kc << 4);
  const char* pb1 = pb0 + (16 << 11);

  f32x4 acc00{}, acc01{}, acc10{}, acc11{};
  auto domfma = [&](const Frag& f) {
    acc00 = MFMA16(f.a0, f.b0, acc00);
    acc01 = MFMA16(f.a0, f.b1, acc01);
    acc10 = MFMA16(f.a1, f.b0, acc10);
    acc11 = MFMA16(f.a1, f.b1, acc11);
  };

#define LOADF(kb, f) do {                              \
    (f).a0 = *(const bf16x8*)(pa0 + (kb) * 64);        \
    (f).a1 = *(const bf16x8*)(pa1 + (kb) * 64);        \
    (f).b0 = *(const bf16x8*)(pb0 + (kb) * 64);        \
    (f).b1 = *(const bf16x8*)(pb1 + (kb) * 64);        \
  } while (0)

  Frag fr[6];
#pragma unroll
  for (int kb = 0; kb < 6; ++kb) LOADF(kb, fr[kb]);
#pragma unroll
  for (int kb = 0; kb < 32; ++kb) {
    domfma(fr[kb % 6]);
    if (kb + 6 < 32) LOADF(kb + 6, fr[kb % 6]);
  }
#undef LOADF

  // ---- epilogue: gather 4 gates per (batch,hidden), LSTM nonlinearity ----
#pragma unroll
  for (int mi = 0; mi < 2; ++mi)
#pragma unroll
    for (int ni = 0; ni < 2; ++ni) {
      f32x4 a = (mi == 0) ? (ni == 0 ? acc00 : acc01) : (ni == 0 ? acc10 : acc11);
#pragma unroll
      for (int r = 0; r < 4; ++r) {
        int row = wm + mi * 16 + ((ln >> 4) << 2) + r;
        int col = wn + ni * 16 + (ln & 15);
        gs[grp * 4352 + row * 68 + col] = a[r];
      }
    }
  __syncthreads();

  const int h = tid & 15, mr = tid >> 4;
  const int hg = (nt << 4) + h;
#pragma unroll
  for (int half = 0; half < 2; ++half) {
    int m = mr + (half << 5);
    int gm = m0 + m;
    float4 v = *(const float4*)(gs + m * 68 + (h << 2));
    float g0 = v.x, g1 = v.y, g2 = v.z, g3 = v.w;
    if (use2) {
      float4 u = *(const float4*)(gs + 4352 + m * 68 + (h << 2));
      g0 += u.x; g1 += u.y; g2 += u.z; g3 += u.w;
    }
    int nb = n0 + (h << 2);
    if (pe) { float4 pv = *(const float4*)(pe + (size_t)gm * 4096 + nb);
              g0 += pv.x; g1 += pv.y; g2 += pv.z; g3 += pv.w; }
    if (bias){ float4 bv = *(const float4*)(bias + nb);
              g0 += bv.x; g1 += bv.y; g2 += bv.z; g3 += bv.w; }
    if (bsub){ float4 sv = *(const float4*)(bsub + nb);
              g0 -= sv.x; g1 -= sv.y; g2 -= sv.z; g3 -= sv.w; }
    float ig = sigm(g0), fg = sigm(g1), gg = ftanh(g2), og = sigm(g3);
    size_t idx = (size_t)gm * 1024 + hg;
    float cn = fg * c_in[idx] + ig * gg;
    c_out[idx] = cn;
    h_out[idx] = __float2bfloat16(og * ftanh(cn));
  }
}

// ---------------------------------------------------------------------------
// Generic 64x64-tile bf16 GEMM C = A @ W.T with epilogues:
// EP0: store bf16 to o1[M][N]            (W_fold build)
// EP1: tanh(v+bias[n]) routed into h1i/h2i (bf16) | c1i/c2i (f32) quadrants
// EP2: f1[m*4096+n] = v + bias[n]        (PE build)
// EP3: f1[b*131072 + gt*512 + n] = v + bias[n], m = gt_local*256+b (outputs)
// ---------------------------------------------------------------------------
template <int EP>
__global__ __launch_bounds__(256) void gemm_ep(
    const bf16* __restrict__ A, const bf16* __restrict__ W, int K,
    const float* __restrict__ bias,
    float* __restrict__ f1, float* __restrict__ f2,
    bf16* __restrict__ o1, bf16* __restrict__ o2, int gt_base)
{
  __shared__ __attribute__((aligned(128))) char smem[32768];
  const int tid = threadIdx.x;
  const int wv = tid >> 6, ln = tid & 63;
  const int n0 = blockIdx.x << 6;
  const int m0 = blockIdx.y << 6;
  const int Nn = (int)(gridDim.x << 6);
  const int wm = (wv >> 1) << 5, wn = (wv & 1) << 5;
  const int nkb = K >> 6;

  f32x4 acc00{}, acc01{}, acc10{}, acc11{};

  auto stage = [&](int kb, int buf) {
    int k0 = kb << 6;
    char* As = smem + buf * 16384;
    char* Bs = As + 8192;
#pragma unroll
    for (int i = 0; i < 2; ++i) {
      int r = ((i << 2) + wv) * 8 + (ln >> 3);
      int sc = (ln & 7) ^ (r & 7);
      gload16((const char*)(A + (size_t)(m0 + r) * K + k0) + (sc << 4),
              As + (((i << 2) + wv) << 10));
      gload16((const char*)(W + (size_t)(n0 + r) * K + k0) + (sc << 4),
              Bs + (((i << 2) + wv) << 10));
    }
  };

  stage(0, 0);
  __syncthreads();
  for (int kb = 0; kb < nkb; ++kb) {
    int buf = kb & 1;
    if (kb + 1 < nkb) stage(kb + 1, buf ^ 1);
    const char* As = smem + buf * 16384;
    const char* Bs = As + 8192;
#pragma unroll
    for (int ks = 0; ks < 2; ++ks) {
      const int kc = (ks << 2) + (ln >> 4);
      auto ld = [&](const char* base, int row) -> bf16x8 {
        return *(const bf16x8*)(base + row * 128 + ((kc ^ (row & 7)) << 4));
      };
      bf16x8 A0 = ld(As, wm + (ln & 15));
      bf16x8 A1 = ld(As, wm + 16 + (ln & 15));
      bf16x8 B0 = ld(Bs, wn + (ln & 15));
      bf16x8 B1 = ld(Bs, wn + 16 + (ln & 15));
      acc00 = MFMA16(A0, B0, acc00);
      acc01 = MFMA16(A0, B1, acc01);
      acc10 = MFMA16(A1, B0, acc10);
      acc11 = MFMA16(A1, B1, acc11);
    }
    __syncthreads();
  }

#pragma unroll
  for (int mi = 0; mi < 2; ++mi)
#pragma unroll
    for (int ni = 0; ni < 2; ++ni) {
      f32x4 a = (mi == 0) ? (ni == 0 ? acc00 : acc01) : (ni == 0 ? acc10 : acc11);
#pragma unroll
      for (int r = 0; r < 4; ++r) {
        int m = m0 + wm + mi * 16 + ((ln >> 4) << 2) + r;
        int n = n0 + wn + ni * 16 + (ln & 15);
        float v = a[r];
        if constexpr (EP == 0) {
          o1[(size_t)m * Nn + n] = __float2bfloat16(v);
        } else if constexpr (EP == 1) {
          v = tanhf(v + bias[n]);
          int q = n >> 10, hh = n & 1023;
          size_t idx = (size_t)m * 1024 + hh;
          if (q == 0)      o1[idx] = __float2bfloat16(v);
          else if (q == 1) o2[idx] = __float2bfloat16(v);
          else if (q == 2) f1[idx] = v;
          else             f2[idx] = v;
        } else if constexpr (EP == 2) {
          f1[(size_t)m * 4096 + n] = v + bias[n];
        } else {
          int b = m & 255, g = (m >> 8) + gt_base;
          f1[(size_t)b * 131072 + (size_t)g * 512 + n] = v + bias[n];
        }
      }
    }
}

// ------------------------- small prep kernels ------------------------------
__global__ void k_conv(const float* __restrict__ s, bf16* __restrict__ d, int n) {
  int i = blockIdx.x * 256 + threadIdx.x;
  if (i < n) d[i] = __float2bfloat16(s[i]);
}
__global__ void k_trans_wout(const float* __restrict__ s, bf16* __restrict__ d) {
  int i = blockIdx.x * 256 + threadIdx.x;
  int l = i >> 9, j = i & 511;
  d[i] = __float2bfloat16(s[(size_t)j * 1024 + l]);
}
__global__ void k_reorder_g(const float* __restrict__ s, bf16* __restrict__ d) {
  int i = blockIdx.x * 256 + threadIdx.x;
  int np = i >> 10, kx = i & 1023;
  int hh = np >> 2, q = np & 3;
  d[i] = __float2bfloat16(s[(size_t)(q * 1024 + hh) * 1024 + kx]);
}
__global__ void k_reorder_c(const float* __restrict__ s, bf16* __restrict__ d, int coloff) {
  int i = blockIdx.x * 256 + threadIdx.x;
  int np = i >> 9, kx = i & 511;
  int hh = np >> 2, q = np & 3;
  d[i] = __float2bfloat16(s[(size_t)(q * 1024 + hh) * 1024 + coloff + kx]);
}
__global__ void k_bias(const float* __restrict__ bih1, const float* __restrict__ bhh1,
                       const float* __restrict__ bih2, const float* __restrict__ bhh2,
                       const float* __restrict__ bo,   const float* __restrict__ Wih1,
                       float* __restrict__ b1r, float* __restrict__ b2r,
                       float* __restrict__ bfr) {
  int n = blockIdx.x * 256 + threadIdx.x;
  int hh = n >> 2, q = n & 3, r = q * 1024 + hh;
  const float* wrow = Wih1 + (size_t)r * 1024 + 512;
  float acc = 0.f;
  for (int j = 0; j < 512; ++j) acc += bo[j] * wrow[j];
  bfr[n] = acc;
  b1r[n] = bih1[r] + bhh1[r] + acc;
  b2r[n] = bih2[r] + bhh2[r];
}
__global__ void k_ratio(float* __restrict__ dst, const int* __restrict__ ep,
                        const int* __restrict__ kv) {
  float kf = (float)kv[0];
  dst[0] = kf / (kf + __expf((float)ep[0] / kf));
}

// ---------------------------------------------------------------------------
extern "C" void kernel_launch(void* const* d_in, const int* in_sizes, int n_in,
                              void* d_out, int out_size, void* d_ws, size_t ws_size,
                              hipStream_t stream) {
  (void)in_sizes; (void)n_in;
  const float* in_c     = (const float*)d_in[0];
  const float* in_Winit = (const float*)d_in[1];
  const float* in_binit = (const float*)d_in[2];
  const float* in_Wih1  = (const float*)d_in[3];
  const float* in_Whh1  = (const float*)d_in[4];
  const float* in_bih1  = (const float*)d_in[5];
  const float* in_bhh1  = (const float*)d_in[6];
  const float* in_Wih2  = (const float*)d_in[7];
  const float* in_Whh2  = (const float*)d_in[8];
  const float* in_bih2  = (const float*)d_in[9];
  const float* in_bhh2  = (const float*)d_in[10];
  const float* in_Wout  = (const float*)d_in[11];
  const float* in_bout  = (const float*)d_in[12];
  const int*   in_epoch = (const int*)d_in[14];
  const int*   in_k     = (const int*)d_in[15];
  float* out = (float*)d_out;

  char* p = (char*)d_ws;
  auto alloc = [&](size_t bytes) { char* q = p; p += (bytes + 255) & ~(size_t)255; return q; };
  bf16* wHH1  = (bf16*)alloc(4096ull * 1024 * 2);
  bf16* wFOLD = (bf16*)alloc(4096ull * 1024 * 2);
  bf16* wIH2  = (bf16*)alloc(4096ull * 1024 * 2);
  bf16* wHH2  = (bf16*)alloc(4096ull * 1024 * 2);
  bf16* wOUT  = (bf16*)alloc(512ull * 1024 * 2);
  bf16* wOUTT = (bf16*)alloc(1024ull * 512 * 2);
  bf16* wINIT = (bf16*)alloc(4096ull * 512 * 2);
  bf16* wIH1C = (bf16*)alloc(4096ull * 512 * 2);
  bf16* wPREV = (bf16*)alloc(4096ull * 512 * 2);
  bf16* cbf   = (bf16*)alloc(4096ull * 512 * 2);
  float* b1r  = (float*)alloc(4096 * 4);
  float* b2r  = (float*)alloc(4096 * 4);
  float* bfr  = (float*)alloc(4096 * 4);
  bf16* h1i   = (bf16*)alloc(16ull * 256 * 1024 * 2);
  bf16* h2i   = (bf16*)alloc(16ull * 256 * 1024 * 2);
  float* c1i  = (float*)alloc(16ull * 256 * 1024 * 4);
  float* c2i  = (float*)alloc(16ull * 256 * 1024 * 4);
  float* PE1  = (float*)alloc(16ull * 256 * 4096 * 4);
  bf16* h1b[2]; float* c1b[2]; float* c2b[2]; bf16* h2b[2];
  for (int i = 0; i < 2; ++i) {
    h1b[i] = (bf16*)alloc(256ull * 1024 * 2);
    c1b[i] = (float*)alloc(256ull * 1024 * 4);
    c2b[i] = (float*)alloc(256ull * 1024 * 4);
    h2b[i] = (bf16*)alloc(256ull * 1024 * 2);
  }
  bf16* hist = (bf16*)alloc(256ull * 256 * 1024 * 2);
  size_t need_full = (size_t)(p - (char*)d_ws);
  bool primary = ws_size >= need_full;

  // ---- prep ----
  k_conv<<<8192, 256, 0, stream>>>(in_c, cbf, 2097152);
  k_conv<<<2048, 256, 0, stream>>>(in_Wout, wOUT, 524288);
  k_conv<<<8192, 256, 0, stream>>>(in_Winit, wINIT, 2097152);
  k_trans_wout<<<2048, 256, 0, stream>>>(in_Wout, wOUTT);
  k_reorder_g<<<16384, 256, 0, stream>>>(in_Whh1, wHH1);
  k_reorder_g<<<16384, 256, 0, stream>>>(in_Wih2, wIH2);
  k_reorder_g<<<16384, 256, 0, stream>>>(in_Whh2, wHH2);
  k_reorder_c<<<8192, 256, 0, stream>>>(in_Wih1, wIH1C, 0);
  k_reorder_c<<<8192, 256, 0, stream>>>(in_Wih1, wPREV, 512);
  k_bias<<<16, 256, 0, stream>>>(in_bih1, in_bhh1, in_bih2, in_bhh2, in_bout,
                                 in_Wih1, b1r, b2r, bfr);
  gemm_ep<0><<<dim3(16, 64), 256, 0, stream>>>(wPREV, wOUTT, 512, nullptr,
                                               nullptr, nullptr, wFOLD, nullptr, 0);
  gemm_ep<1><<<dim3(64, 64), 256, 0, stream>>>(cbf, wINIT, 512, in_binit,
                                               c1i, c2i, h1i, h2i, 0);
  gemm_ep<2><<<dim3(64, 64), 256, 0, stream>>>(cbf, wIH1C, 512, b1r,
                                               PE1, nullptr, nullptr, nullptr, 0);

  // ---- recurrence: 16 segments x 16 steps, 2 GEMM launches each ----
  const size_t S = 256ull * 1024;
  for (int s = 0; s < 16; ++s) {
    for (int t = 0; t < 16; ++t) {
      int gt = s * 16 + t;
      int cur = gt & 1, prv = cur ^ 1;
      const bf16* h2prev = (gt == 0) ? nullptr
                          : (primary ? hist + (size_t)(gt - 1) * S : h2b[prv]);
      // layer 1: g1 = PE1[s] + h1@W_hh1' + h2prev@W_fold'  (-b_fold at gt==0)
      rnn_step<<<256, 512, 0, stream>>>(
          (t == 0) ? h1i + (size_t)s * S : h1b[prv], h2prev,
          wHH1, wFOLD,
          PE1 + (size_t)s * 1048576, nullptr, (gt == 0) ? bfr : nullptr,
          (t == 0) ? c1i + (size_t)s * S : c1b[prv], c1b[cur], h1b[cur]);
      // layer 2: g2 = h1n@W_ih2' + h2@W_hh2' + b2
      rnn_step<<<256, 512, 0, stream>>>(
          h1b[cur],
          (t == 0) ? h2i + (size_t)s * S
                   : (primary ? hist + (size_t)(gt - 1) * S : h2b[prv]),
          wIH2, wHH2, nullptr, b2r, nullptr,
          (t == 0) ? c2i + (size_t)s * S : c2b[prv], c2b[cur],
          primary ? hist + (size_t)gt * S : h2b[cur]);
      if (!primary) {
        gemm_ep<3><<<dim3(8, 4), 256, 0, stream>>>(h2b[cur], wOUT, 1024, in_bout,
                                                   out, nullptr, nullptr, nullptr, gt);
      }
    }
  }

  // ---- outputs: one big GEMM over the h2 history ----
  if (primary) {
    gemm_ep<3><<<dim3(8, 1024), 256, 0, stream>>>(hist, wOUT, 1024, in_bout,
                                                  out, nullptr, nullptr, nullptr, 0);
  }
  k_ratio<<<1, 1, 0, stream>>>(out + (out_size - 1), in_epoch, in_k);
}

// Round 8
// 8379.726 us; speedup vs baseline: 2.4534x; 2.4534x over previous
//
#include <hip/hip_runtime.h>
#include <hip/hip_bf16.h>

using bf16 = __hip_bfloat16;
typedef __attribute__((ext_vector_type(8))) short bf16x8;
typedef __attribute__((ext_vector_type(4))) float f32x4;

__device__ __forceinline__ void gload16(const void* g, void* l) {
  __builtin_amdgcn_global_load_lds((const __attribute__((address_space(1))) void*)g,
                                   (__attribute__((address_space(3))) void*)l, 16, 0, 0);
}

__device__ __forceinline__ float sigm(float x) { return 1.0f / (1.0f + __expf(-x)); }
// overflow-safe fast tanh
__device__ __forceinline__ float ftanh(float x) {
  float e = __expf(2.0f * fabsf(x));
  return copysignf(1.0f - 2.0f / (e + 1.0f), x);
}

#define MFMA16(a, b, c) __builtin_amdgcn_mfma_f32_16x16x32_bf16(a, b, c, 0, 0, 0)

struct Frag { bf16x8 a0, a1, b0, b1; };

// Fragment-major ("permuted") layout for a [M][1024] bf16 matrix:
// elem(m,k) -> ((m>>5)*128 + (k>>3))*256 + (m&31)*8 + (k&7)
// A wave's 16x16x32-MFMA fragment (lane l: row l&15, k-chunk l>>4) is then a
// fully-contiguous 1KB burst per 16-row block.

// ---------------------------------------------------------------------------
// Recurrent step GEMM: g[256,4096] = pe + a1@w1.T + a2@w2.T (+bias -bsub),
// fused LSTM-gate epilogue (weights gate-interleaved: col n = 4*h + q).
// 512 threads: wave-group 0 (waves 0-3) does a1@w1 (K=1024), group 1 a2@w2.
// K-loop: NO LDS, NO barriers — fragments loaded global->VGPR from permuted
// layouts (contiguous bursts, L1/L2-hot), depth-8 register pipeline, fully
// unrolled (static frag ring). Waves run decoupled until the epilogue.
// grid 256 linear (XCD-decoded), block 512.
// ---------------------------------------------------------------------------
__global__ __launch_bounds__(512) void rnn_step(
    const bf16* __restrict__ a1, const bf16* __restrict__ a2,
    const bf16* __restrict__ w1, const bf16* __restrict__ w2,
    const float* __restrict__ pe, const float* __restrict__ bias,
    const float* __restrict__ bsub,
    const float* __restrict__ c_in, float* __restrict__ c_out,
    bf16* __restrict__ hp_out, bf16* __restrict__ hrow_out)
{
  __shared__ __attribute__((aligned(128))) float gs[2 * 64 * 68];  // 34KB
  const int tid = threadIdx.x;
  const int wv = tid >> 6, ln = tid & 63;
  const int grp = wv >> 2, wg = wv & 3;
  // XCD-aware decode: blocks sharing a B-panel (same nt) land on one XCD.
  const int bid = blockIdx.x;
  const int nt = ((bid & 7) << 3) | ((bid >> 3) & 7);
  const int mt = bid >> 6;
  const int m0 = mt << 6, n0 = nt << 6;
  const int wm = (wg >> 1) << 5, wn = (wg & 1) << 5;
  const bool use2 = (a2 != nullptr);

  const bf16* asrc = (grp == 0) ? a1 : (use2 ? a2 : a1);
  const bf16* wsrc = (grp == 0) ? w1 : (use2 ? w2 : w1);

  // per-lane fragment base addrs in permuted layout
  const int r16 = ln & 15, c4 = ln >> 4;
  const int mgA = m0 + wm + r16;
  const int ngB = n0 + wn + r16;
  const char* pa = (const char*)asrc +
      ((size_t)(mgA >> 5) * 128 + c4) * 512 + (size_t)(mgA & 31) * 16;
  const char* pb = (const char*)wsrc +
      ((size_t)(ngB >> 5) * 128 + c4) * 512 + (size_t)(ngB & 31) * 16;

  f32x4 acc00{}, acc01{}, acc10{}, acc11{};
  Frag fr[8];
#define LOADF(kb, f) do {                               \
    (f).a0 = *(const bf16x8*)(pa + (kb) * 2048);        \
    (f).a1 = *(const bf16x8*)(pa + (kb) * 2048 + 256);  \
    (f).b0 = *(const bf16x8*)(pb + (kb) * 2048);        \
    (f).b1 = *(const bf16x8*)(pb + (kb) * 2048 + 256);  \
  } while (0)
#pragma unroll
  for (int kb = 0; kb < 8; ++kb) LOADF(kb, fr[kb]);
#pragma unroll
  for (int kb = 0; kb < 32; ++kb) {
    Frag& f = fr[kb & 7];
    acc00 = MFMA16(f.a0, f.b0, acc00);
    acc01 = MFMA16(f.a0, f.b1, acc01);
    acc10 = MFMA16(f.a1, f.b0, acc10);
    acc11 = MFMA16(f.a1, f.b1, acc11);
    if (kb + 8 < 32) LOADF(kb + 8, f);
  }
#undef LOADF

  // ---- epilogue: gather 4 gates per (batch,hidden), LSTM nonlinearity ----
#pragma unroll
  for (int mi = 0; mi < 2; ++mi)
#pragma unroll
    for (int ni = 0; ni < 2; ++ni) {
      f32x4 a = (mi == 0) ? (ni == 0 ? acc00 : acc01) : (ni == 0 ? acc10 : acc11);
#pragma unroll
      for (int r = 0; r < 4; ++r) {
        int row = wm + mi * 16 + ((ln >> 4) << 2) + r;
        int col = wn + ni * 16 + (ln & 15);
        gs[grp * 4352 + row * 68 + col] = a[r];
      }
    }
  __syncthreads();

  const int h = tid & 15, mr = tid >> 4;
  const int hg = (nt << 4) + h;
#pragma unroll
  for (int half = 0; half < 2; ++half) {
    int m = mr + (half << 5);
    int gm = m0 + m;
    float4 v = *(const float4*)(gs + m * 68 + (h << 2));
    float g0 = v.x, g1 = v.y, g2 = v.z, g3 = v.w;
    if (use2) {
      float4 u = *(const float4*)(gs + 4352 + m * 68 + (h << 2));
      g0 += u.x; g1 += u.y; g2 += u.z; g3 += u.w;
    }
    int nb = n0 + (h << 2);
    if (pe) { float4 pv = *(const float4*)(pe + (size_t)gm * 4096 + nb);
              g0 += pv.x; g1 += pv.y; g2 += pv.z; g3 += pv.w; }
    if (bias){ float4 bv = *(const float4*)(bias + nb);
              g0 += bv.x; g1 += bv.y; g2 += bv.z; g3 += bv.w; }
    if (bsub){ float4 sv = *(const float4*)(bsub + nb);
              g0 -= sv.x; g1 -= sv.y; g2 -= sv.z; g3 -= sv.w; }
    float ig = sigm(g0), fg = sigm(g1), gg = ftanh(g2), og = sigm(g3);
    size_t idx = (size_t)gm * 1024 + hg;
    float cn = fg * c_in[idx] + ig * gg;
    c_out[idx] = cn;
    bf16 hv = __float2bfloat16(og * ftanh(cn));
    hp_out[((size_t)(gm >> 5) * 128 + (hg >> 3)) * 256 + (gm & 31) * 8 + (hg & 7)] = hv;
    if (hrow_out) hrow_out[idx] = hv;
  }
}

// ---------------------------------------------------------------------------
// Generic 64x64-tile bf16 GEMM C = A @ W.T with epilogues:
// EP0: store bf16 PERMUTED to o1 (fragment-major, KC=Nn>>3)   (W_fold build)
// EP1: tanh(v+bias[n]); h1i/h2i written PERMUTED per segment; c1i/c2i f32
// EP2: f1[m*4096+n] = v + bias[n]        (PE build)
// EP3: f1[b*131072 + gt*512 + n] = v + bias[n], m = gt_local*256+b (outputs)
// ---------------------------------------------------------------------------
template <int EP>
__global__ __launch_bounds__(256) void gemm_ep(
    const bf16* __restrict__ A, const bf16* __restrict__ W, int K,
    const float* __restrict__ bias,
    float* __restrict__ f1, float* __restrict__ f2,
    bf16* __restrict__ o1, bf16* __restrict__ o2, int gt_base)
{
  __shared__ __attribute__((aligned(128))) char smem[32768];
  const int tid = threadIdx.x;
  const int wv = tid >> 6, ln = tid & 63;
  const int n0 = blockIdx.x << 6;
  const int m0 = blockIdx.y << 6;
  const int Nn = (int)(gridDim.x << 6);
  const int wm = (wv >> 1) << 5, wn = (wv & 1) << 5;
  const int nkb = K >> 6;

  f32x4 acc00{}, acc01{}, acc10{}, acc11{};

  auto stage = [&](int kb, int buf) {
    int k0 = kb << 6;
    char* As = smem + buf * 16384;
    char* Bs = As + 8192;
#pragma unroll
    for (int i = 0; i < 2; ++i) {
      int r = ((i << 2) + wv) * 8 + (ln >> 3);
      int sc = (ln & 7) ^ (r & 7);
      gload16((const char*)(A + (size_t)(m0 + r) * K + k0) + (sc << 4),
              As + (((i << 2) + wv) << 10));
      gload16((const char*)(W + (size_t)(n0 + r) * K + k0) + (sc << 4),
              Bs + (((i << 2) + wv) << 10));
    }
  };

  stage(0, 0);
  __syncthreads();
  for (int kb = 0; kb < nkb; ++kb) {
    int buf = kb & 1;
    if (kb + 1 < nkb) stage(kb + 1, buf ^ 1);
    const char* As = smem + buf * 16384;
    const char* Bs = As + 8192;
#pragma unroll
    for (int ks = 0; ks < 2; ++ks) {
      const int kc = (ks << 2) + (ln >> 4);
      auto ld = [&](const char* base, int row) -> bf16x8 {
        return *(const bf16x8*)(base + row * 128 + ((kc ^ (row & 7)) << 4));
      };
      bf16x8 A0 = ld(As, wm + (ln & 15));
      bf16x8 A1 = ld(As, wm + 16 + (ln & 15));
      bf16x8 B0 = ld(Bs, wn + (ln & 15));
      bf16x8 B1 = ld(Bs, wn + 16 + (ln & 15));
      acc00 = MFMA16(A0, B0, acc00);
      acc01 = MFMA16(A0, B1, acc01);
      acc10 = MFMA16(A1, B0, acc10);
      acc11 = MFMA16(A1, B1, acc11);
    }
    __syncthreads();
  }

#pragma unroll
  for (int mi = 0; mi < 2; ++mi)
#pragma unroll
    for (int ni = 0; ni < 2; ++ni) {
      f32x4 a = (mi == 0) ? (ni == 0 ? acc00 : acc01) : (ni == 0 ? acc10 : acc11);
#pragma unroll
      for (int r = 0; r < 4; ++r) {
        int m = m0 + wm + mi * 16 + ((ln >> 4) << 2) + r;
        int n = n0 + wn + ni * 16 + (ln & 15);
        float v = a[r];
        if constexpr (EP == 0) {
          o1[((size_t)(m >> 5) * (Nn >> 3) + (n >> 3)) * 256 + (m & 31) * 8 + (n & 7)]
              = __float2bfloat16(v);
        } else if constexpr (EP == 1) {
          v = tanhf(v + bias[n]);
          int q = n >> 10, hh = n & 1023;
          int sseg = m >> 8, b = m & 255;
          size_t pidx = (size_t)sseg * 262144 +
              ((size_t)(b >> 5) * 128 + (hh >> 3)) * 256 + (b & 31) * 8 + (hh & 7);
          size_t idx = (size_t)m * 1024 + hh;
          if (q == 0)      o1[pidx] = __float2bfloat16(v);
          else if (q == 1) o2[pidx] = __float2bfloat16(v);
          else if (q == 2) f1[idx] = v;
          else             f2[idx] = v;
        } else if constexpr (EP == 2) {
          f1[(size_t)m * 4096 + n] = v + bias[n];
        } else {
          int b = m & 255, g = (m >> 8) + gt_base;
          f1[(size_t)b * 131072 + (size_t)g * 512 + n] = v + bias[n];
        }
      }
    }
}

// ------------------------- small prep kernels ------------------------------
__global__ void k_conv(const float* __restrict__ s, bf16* __restrict__ d, int n) {
  int i = blockIdx.x * 256 + threadIdx.x;
  if (i < n) d[i] = __float2bfloat16(s[i]);
}
__global__ void k_trans_wout(const float* __restrict__ s, bf16* __restrict__ d) {
  int i = blockIdx.x * 256 + threadIdx.x;
  int l = i >> 9, j = i & 511;
  d[i] = __float2bfloat16(s[(size_t)j * 1024 + l]);
}
// gate-interleaved reorder + fragment-major permute: logical (np, kx) with
// np = 4h+q <- src row q*1024+h; dst elem = perm(np, kx), K=1024
__global__ void k_reorder_g(const float* __restrict__ s, bf16* __restrict__ d) {
  int i = blockIdx.x * 256 + threadIdx.x;  // 4096*1024 logical
  int np = i >> 10, kx = i & 1023;
  int hh = np >> 2, q = np & 3;
  size_t dst = ((size_t)(np >> 5) * 128 + (kx >> 3)) * 256 + (np & 31) * 8 + (kx & 7);
  d[dst] = __float2bfloat16(s[(size_t)(q * 1024 + hh) * 1024 + kx]);
}
// row-major 512-wide slice of W_ih1 (still consumed by LDS-based gemm_ep)
__global__ void k_reorder_c(const float* __restrict__ s, bf16* __restrict__ d, int coloff) {
  int i = blockIdx.x * 256 + threadIdx.x;
  int np = i >> 9, kx = i & 511;
  int hh = np >> 2, q = np & 3;
  d[i] = __float2bfloat16(s[(size_t)(q * 1024 + hh) * 1024 + coloff + kx]);
}
__global__ void k_bias(const float* __restrict__ bih1, const float* __restrict__ bhh1,
                       const float* __restrict__ bih2, const float* __restrict__ bhh2,
                       const float* __restrict__ bo,   const float* __restrict__ Wih1,
                       float* __restrict__ b1r, float* __restrict__ b2r,
                       float* __restrict__ bfr) {
  int n = blockIdx.x * 256 + threadIdx.x;
  int hh = n >> 2, q = n & 3, r = q * 1024 + hh;
  const float* wrow = Wih1 + (size_t)r * 1024 + 512;
  float acc = 0.f;
  for (int j = 0; j < 512; ++j) acc += bo[j] * wrow[j];
  bfr[n] = acc;
  b1r[n] = bih1[r] + bhh1[r] + acc;
  b2r[n] = bih2[r] + bhh2[r];
}
__global__ void k_ratio(float* __restrict__ dst, const int* __restrict__ ep,
                        const int* __restrict__ kv) {
  float kf = (float)kv[0];
  dst[0] = kf / (kf + __expf((float)ep[0] / kf));
}

// ---------------------------------------------------------------------------
extern "C" void kernel_launch(void* const* d_in, const int* in_sizes, int n_in,
                              void* d_out, int out_size, void* d_ws, size_t ws_size,
                              hipStream_t stream) {
  (void)in_sizes; (void)n_in; (void)ws_size;
  const float* in_c     = (const float*)d_in[0];
  const float* in_Winit = (const float*)d_in[1];
  const float* in_binit = (const float*)d_in[2];
  const float* in_Wih1  = (const float*)d_in[3];
  const float* in_Whh1  = (const float*)d_in[4];
  const float* in_bih1  = (const float*)d_in[5];
  const float* in_bhh1  = (const float*)d_in[6];
  const float* in_Wih2  = (const float*)d_in[7];
  const float* in_Whh2  = (const float*)d_in[8];
  const float* in_bih2  = (const float*)d_in[9];
  const float* in_bhh2  = (const float*)d_in[10];
  const float* in_Wout  = (const float*)d_in[11];
  const float* in_bout  = (const float*)d_in[12];
  const int*   in_epoch = (const int*)d_in[14];
  const int*   in_k     = (const int*)d_in[15];
  float* out = (float*)d_out;

  char* p = (char*)d_ws;
  auto alloc = [&](size_t bytes) { char* q = p; p += (bytes + 255) & ~(size_t)255; return q; };
  bf16* wHH1  = (bf16*)alloc(4096ull * 1024 * 2);   // permuted
  bf16* wFOLD = (bf16*)alloc(4096ull * 1024 * 2);   // permuted (via EP0)
  bf16* wIH2  = (bf16*)alloc(4096ull * 1024 * 2);   // permuted
  bf16* wHH2  = (bf16*)alloc(4096ull * 1024 * 2);   // permuted
  bf16* wOUT  = (bf16*)alloc(512ull * 1024 * 2);    // row-major
  bf16* wOUTT = (bf16*)alloc(1024ull * 512 * 2);    // row-major
  bf16* wINIT = (bf16*)alloc(4096ull * 512 * 2);    // row-major
  bf16* wIH1C = (bf16*)alloc(4096ull * 512 * 2);    // row-major
  bf16* wPREV = (bf16*)alloc(4096ull * 512 * 2);    // row-major
  bf16* cbf   = (bf16*)alloc(4096ull * 512 * 2);
  float* b1r  = (float*)alloc(4096 * 4);
  float* b2r  = (float*)alloc(4096 * 4);
  float* bfr  = (float*)alloc(4096 * 4);
  bf16* h1i   = (bf16*)alloc(16ull * 256 * 1024 * 2);   // permuted per segment
  bf16* h2i   = (bf16*)alloc(16ull * 256 * 1024 * 2);   // permuted per segment
  float* c1i  = (float*)alloc(16ull * 256 * 1024 * 4);  // row-major
  float* c2i  = (float*)alloc(16ull * 256 * 1024 * 4);  // row-major
  float* PE1  = (float*)alloc(16ull * 256 * 4096 * 4);
  bf16* h1p[2]; bf16* h2p[2]; float* c1b[2]; float* c2b[2];
  for (int i = 0; i < 2; ++i) {
    h1p[i] = (bf16*)alloc(256ull * 1024 * 2);   // permuted
    h2p[i] = (bf16*)alloc(256ull * 1024 * 2);   // permuted
    c1b[i] = (float*)alloc(256ull * 1024 * 4);
    c2b[i] = (float*)alloc(256ull * 1024 * 4);
  }
  bf16* hist = (bf16*)alloc(256ull * 256 * 1024 * 2);   // row-major

  // ---- prep ----
  k_conv<<<8192, 256, 0, stream>>>(in_c, cbf, 2097152);
  k_conv<<<2048, 256, 0, stream>>>(in_Wout, wOUT, 524288);
  k_conv<<<8192, 256, 0, stream>>>(in_Winit, wINIT, 2097152);
  k_trans_wout<<<2048, 256, 0, stream>>>(in_Wout, wOUTT);
  k_reorder_g<<<16384, 256, 0, stream>>>(in_Whh1, wHH1);
  k_reorder_g<<<16384, 256, 0, stream>>>(in_Wih2, wIH2);
  k_reorder_g<<<16384, 256, 0, stream>>>(in_Whh2, wHH2);
  k_reorder_c<<<8192, 256, 0, stream>>>(in_Wih1, wIH1C, 0);
  k_reorder_c<<<8192, 256, 0, stream>>>(in_Wih1, wPREV, 512);
  k_bias<<<16, 256, 0, stream>>>(in_bih1, in_bhh1, in_bih2, in_bhh2, in_bout,
                                 in_Wih1, b1r, b2r, bfr);
  // W_fold (permuted) = Wp_r @ W_out   (M=4096,N=1024,K=512)
  gemm_ep<0><<<dim3(16, 64), 256, 0, stream>>>(wPREV, wOUTT, 512, nullptr,
                                               nullptr, nullptr, wFOLD, nullptr, 0);
  // init states: tanh(c @ W_init.T + b_init) -> h1i/h2i permuted, c1i/c2i f32
  gemm_ep<1><<<dim3(64, 64), 256, 0, stream>>>(cbf, wINIT, 512, in_binit,
                                               c1i, c2i, h1i, h2i, 0);
  // PE1[s][b][n'] = embed @ W_ih1_cond.T + (b_ih1+b_hh1+b_fold)
  gemm_ep<2><<<dim3(64, 64), 256, 0, stream>>>(cbf, wIH1C, 512, b1r,
                                               PE1, nullptr, nullptr, nullptr, 0);

  // ---- recurrence: 16 segments x 16 steps, 2 GEMM launches each ----
  const size_t S = 256ull * 1024;
  for (int s = 0; s < 16; ++s) {
    for (int t = 0; t < 16; ++t) {
      int gt = s * 16 + t;
      int cur = gt & 1, prv = cur ^ 1;
      // prev carries ACROSS segment boundaries: layer-1's folded operand is
      // always the previous step's h2 (h2p[prv]), even at t==0. (Round-7 bug:
      // used fresh h2i at t==0.)
      const bf16* h2prev = (gt == 0) ? nullptr : h2p[prv];
      // layer 1: g1 = PE1[s] + h1@W_hh1' + h2prev@W_fold'  (-b_fold at gt==0)
      rnn_step<<<256, 512, 0, stream>>>(
          (t == 0) ? h1i + (size_t)s * S : h1p[prv], h2prev,
          wHH1, wFOLD,
          PE1 + (size_t)s * 1048576, nullptr, (gt == 0) ? bfr : nullptr,
          (t == 0) ? c1i + (size_t)s * S : c1b[prv], c1b[cur],
          h1p[cur], nullptr);
      // layer 2: g2 = h1new@W_ih2' + h2@W_hh2' + b2   (h2 state IS re-init at t==0)
      rnn_step<<<256, 512, 0, stream>>>(
          h1p[cur],
          (t == 0) ? h2i + (size_t)s * S : h2p[prv],
          wIH2, wHH2, nullptr, b2r, nullptr,
          (t == 0) ? c2i + (size_t)s * S : c2b[prv], c2b[cur],
          h2p[cur], hist + (size_t)gt * S);
    }
  }

  // ---- outputs: one big GEMM over the row-major h2 history ----
  gemm_ep<3><<<dim3(8, 1024), 256, 0, stream>>>(hist, wOUT, 1024, in_bout,
                                                out, nullptr, nullptr, nullptr, 0);
  k_ratio<<<1, 1, 0, stream>>>(out + (out_size - 1), in_epoch, in_k);
}

// Round 9
// 6681.921 us; speedup vs baseline: 3.0768x; 1.2541x over previous
//
#include <hip/hip_runtime.h>
#include <hip/hip_bf16.h>

using bf16 = __hip_bfloat16;
typedef __attribute__((ext_vector_type(8))) short bf16x8;
typedef __attribute__((ext_vector_type(4))) float f32x4;

__device__ __forceinline__ void gload16(const void* g, void* l) {
  __builtin_amdgcn_global_load_lds((const __attribute__((address_space(1))) void*)g,
                                   (__attribute__((address_space(3))) void*)l, 16, 0, 0);
}

__device__ __forceinline__ float sigm(float x) { return 1.0f / (1.0f + __expf(-x)); }
// overflow-safe fast tanh
__device__ __forceinline__ float ftanh(float x) {
  float e = __expf(2.0f * fabsf(x));
  return copysignf(1.0f - 2.0f / (e + 1.0f), x);
}

#define MFMA16(a, b, c) __builtin_amdgcn_mfma_f32_16x16x32_bf16(a, b, c, 0, 0, 0)

struct FragA { bf16x8 a00, a10, a01, a11; };  // 2 m-frags x 2 kb of a pair

// Fragment-major ("permuted") layout for a [M][1024] bf16 matrix:
// elem(m,k) -> ((m>>5)*128 + (k>>3))*256 + (m&31)*8 + (k&7)
// A wave's 16x16x32 A-fragment is then one contiguous 1KB burst.

// ---------------------------------------------------------------------------
// Recurrent step GEMM: g[256,4096] = pe + a1@w1.T + a2@w2.T (+bias -bsub),
// fused LSTM-gate epilogue (weights gate-interleaved: col n = 4*h + q).
// 512 threads: wave-group 0 (waves 0-3) does a1@w1 (K=1024), group 1 a2@w2.
// HYBRID dataflow: B (weights, row-major) staged via global_load_lds into a
// 4-deep pair-slot LDS ring (swizzled); A (h-states, fragment-major permuted)
// loaded DIRECTLY global->VGPR (contiguous 1KB bursts, L2-resident) -- halves
// LDS-port traffic and runs the two memory ports in parallel.
// Counted-vmcnt schedule: B depth 3 pairs, A depth 2 pairs, 1 barrier/pair.
// grid 256 linear (XCD-decoded), block 512.
// ---------------------------------------------------------------------------
__global__ __launch_bounds__(512) void rnn_step(
    const bf16* __restrict__ a1, const bf16* __restrict__ a2,
    const bf16* __restrict__ w1, const bf16* __restrict__ w2,
    const float* __restrict__ pe, const float* __restrict__ bias,
    const float* __restrict__ bsub,
    const float* __restrict__ c_in, float* __restrict__ c_out,
    bf16* __restrict__ hp_out, bf16* __restrict__ hrow_out)
{
  __shared__ __attribute__((aligned(128))) char smem[65536];
  const int tid = threadIdx.x;
  const int wv = tid >> 6, ln = tid & 63;
  const int grp = wv >> 2, wg = wv & 3;
  // XCD-aware decode: blocks sharing a B-panel (same nt) land on one XCD.
  const int bid = blockIdx.x;
  const int nt = ((bid & 7) << 3) | ((bid >> 3) & 7);
  const int mt = bid >> 6;
  const int m0 = mt << 6, n0 = nt << 6;
  const int wm = (wg >> 1) << 5, wn = (wg & 1) << 5;
  const bool use2 = (a2 != nullptr);

  const bf16* asrc = (grp == 0) ? a1 : (use2 ? a2 : a1);
  const bf16* wsrc = (grp == 0) ? w1 : (use2 ? w2 : w1);
  char* ring = smem + (grp << 15);  // 32KB/group: 4 pair-slots x 8KB

  // ---- B staging (row-major weights, row stride 2048B) ----
  const int srow = (wg << 4) + (ln >> 2);          // tile n-row this lane fills
  const int skc  = (ln & 3) ^ ((srow >> 1) & 3);   // pre-swizzled 16B chunk
  const char* bsrcB = (const char*)wsrc + (size_t)(n0 + srow) * 2048 + (skc << 4);
#define STAGEB(p) do {                                        \
    char* d = ring + (((p) & 3) << 13) + (wg << 10);          \
    gload16(bsrcB + (p) * 128,      d);                       \
    gload16(bsrcB + (p) * 128 + 64, d + 4096);                \
  } while (0)

  // ---- A direct loads (fragment-major permuted) ----
  const int r16 = ln & 15, kc4 = ln >> 4;
  const int mgA = m0 + wm + r16;
  const char* pa = (const char*)asrc +
      ((size_t)(mgA >> 5) * 128 + kc4) * 512 + (size_t)(mgA & 31) * 16;
#define LOADA(p, f) do {                                              \
    (f).a00 = *(const bf16x8*)(pa + (size_t)(2 * (p)) * 2048);        \
    (f).a10 = *(const bf16x8*)(pa + (size_t)(2 * (p)) * 2048 + 256);  \
    (f).a01 = *(const bf16x8*)(pa + (size_t)(2 * (p) + 1) * 2048);       \
    (f).a11 = *(const bf16x8*)(pa + (size_t)(2 * (p) + 1) * 2048 + 256); \
  } while (0)

  // ---- B read offsets (swizzled) ----
  const int br0 = wn + r16, br1 = br0 + 16;
  const int boff0 = br0 * 64 + ((kc4 ^ ((br0 >> 1) & 3)) << 4);
  const int boff1 = br1 * 64 + ((kc4 ^ ((br1 >> 1) & 3)) << 4);

  f32x4 acc00{}, acc01{}, acc10{}, acc11{};

#define PAIR(p, WN, fU, fL, DOSTAGE, DOLOAD) do {                      \
    asm volatile("s_waitcnt vmcnt(" #WN ")" ::: "memory");             \
    __builtin_amdgcn_s_barrier();                                      \
    asm volatile("" ::: "memory");                                     \
    if (DOSTAGE) STAGEB((p) + 3);                                      \
    if (DOLOAD) LOADA((p) + 2, fL);                                    \
    __builtin_amdgcn_s_setprio(1);                                     \
    {                                                                  \
      const char* base = ring + (((p) & 3) << 13);                     \
      bf16x8 b00 = *(const bf16x8*)(base + boff0);                     \
      bf16x8 b10 = *(const bf16x8*)(base + boff1);                     \
      bf16x8 b01 = *(const bf16x8*)(base + 4096 + boff0);              \
      bf16x8 b11 = *(const bf16x8*)(base + 4096 + boff1);              \
      acc00 = MFMA16(fU.a00, b00, acc00);                              \
      acc01 = MFMA16(fU.a00, b10, acc01);                              \
      acc10 = MFMA16(fU.a10, b00, acc10);                              \
      acc11 = MFMA16(fU.a10, b10, acc11);                              \
      acc00 = MFMA16(fU.a01, b01, acc00);                              \
      acc01 = MFMA16(fU.a01, b11, acc01);                              \
      acc10 = MFMA16(fU.a11, b01, acc10);                              \
      acc11 = MFMA16(fU.a11, b11, acc11);                              \
    }                                                                  \
    __builtin_amdgcn_s_setprio(0);                                     \
  } while (0)

  FragA fA0, fA1, fA2;
  // prologue: queue = B0 A0 B1 A1 B2 (14 ops in flight)
  STAGEB(0); LOADA(0, fA0);
  STAGEB(1); LOADA(1, fA1);
  STAGEB(2);
  PAIR(0,  8, fA0, fA2, 1, 1);
  PAIR(1,  8, fA1, fA0, 1, 1);
  PAIR(2,  6, fA2, fA1, 1, 1);
  PAIR(3,  6, fA0, fA2, 1, 1);
  PAIR(4,  6, fA1, fA0, 1, 1);
  PAIR(5,  6, fA2, fA1, 1, 1);
  PAIR(6,  6, fA0, fA2, 1, 1);
  PAIR(7,  6, fA1, fA0, 1, 1);
  PAIR(8,  6, fA2, fA1, 1, 1);
  PAIR(9,  6, fA0, fA2, 1, 1);
  PAIR(10, 6, fA1, fA0, 1, 1);
  PAIR(11, 6, fA2, fA1, 1, 1);
  PAIR(12, 6, fA0, fA2, 1, 1);
  PAIR(13, 6, fA1, fA0, 0, 1);
  PAIR(14, 4, fA2, fA0, 0, 0);
  PAIR(15, 0, fA0, fA0, 0, 0);
#undef PAIR
#undef LOADA
#undef STAGEB

  // ---- epilogue: gather 4 gates per (batch,hidden), LSTM nonlinearity ----
  __syncthreads();  // all ring reads done before gs overwrites smem
  float* gs = (float*)smem;  // [2][64][68]
#pragma unroll
  for (int mi = 0; mi < 2; ++mi)
#pragma unroll
    for (int ni = 0; ni < 2; ++ni) {
      f32x4 a = (mi == 0) ? (ni == 0 ? acc00 : acc01) : (ni == 0 ? acc10 : acc11);
#pragma unroll
      for (int r = 0; r < 4; ++r) {
        int row = wm + mi * 16 + ((ln >> 4) << 2) + r;
        int col = wn + ni * 16 + (ln & 15);
        gs[grp * 4352 + row * 68 + col] = a[r];
      }
    }
  __syncthreads();

  const int h = tid & 15, mr = tid >> 4;
  const int hg = (nt << 4) + h;
#pragma unroll
  for (int half = 0; half < 2; ++half) {
    int m = mr + (half << 5);
    int gm = m0 + m;
    float4 v = *(const float4*)(gs + m * 68 + (h << 2));
    float g0 = v.x, g1 = v.y, g2 = v.z, g3 = v.w;
    if (use2) {
      float4 u = *(const float4*)(gs + 4352 + m * 68 + (h << 2));
      g0 += u.x; g1 += u.y; g2 += u.z; g3 += u.w;
    }
    int nb = n0 + (h << 2);
    if (pe) { float4 pv = *(const float4*)(pe + (size_t)gm * 4096 + nb);
              g0 += pv.x; g1 += pv.y; g2 += pv.z; g3 += pv.w; }
    if (bias){ float4 bv = *(const float4*)(bias + nb);
              g0 += bv.x; g1 += bv.y; g2 += bv.z; g3 += bv.w; }
    if (bsub){ float4 sv = *(const float4*)(bsub + nb);
              g0 -= sv.x; g1 -= sv.y; g2 -= sv.z; g3 -= sv.w; }
    float ig = sigm(g0), fg = sigm(g1), gg = ftanh(g2), og = sigm(g3);
    size_t idx = (size_t)gm * 1024 + hg;
    float cn = fg * c_in[idx] + ig * gg;
    c_out[idx] = cn;
    bf16 hv = __float2bfloat16(og * ftanh(cn));
    hp_out[((size_t)(gm >> 5) * 128 + (hg >> 3)) * 256 + (gm & 31) * 8 + (hg & 7)] = hv;
    if (hrow_out) hrow_out[idx] = hv;
  }
}

// ---------------------------------------------------------------------------
// Generic 64x64-tile bf16 GEMM C = A @ W.T with epilogues:
// EP0: store bf16 row-major to o1[M][N]  (W_fold build -- staged as B later)
// EP1: tanh(v+bias[n]); h1i/h2i written PERMUTED per segment; c1i/c2i f32
// EP2: f1[m*4096+n] = v + bias[n]        (PE build)
// EP3: f1[b*131072 + gt*512 + n] = v + bias[n], m = gt_local*256+b (outputs)
// ---------------------------------------------------------------------------
template <int EP>
__global__ __launch_bounds__(256) void gemm_ep(
    const bf16* __restrict__ A, const bf16* __restrict__ W, int K,
    const float* __restrict__ bias,
    float* __restrict__ f1, float* __restrict__ f2,
    bf16* __restrict__ o1, bf16* __restrict__ o2, int gt_base)
{
  __shared__ __attribute__((aligned(128))) char smem[32768];
  const int tid = threadIdx.x;
  const int wv = tid >> 6, ln = tid & 63;
  const int n0 = blockIdx.x << 6;
  const int m0 = blockIdx.y << 6;
  const int Nn = (int)(gridDim.x << 6);
  const int wm = (wv >> 1) << 5, wn = (wv & 1) << 5;
  const int nkb = K >> 6;

  f32x4 acc00{}, acc01{}, acc10{}, acc11{};

  auto stage = [&](int kb, int buf) {
    int k0 = kb << 6;
    char* As = smem + buf * 16384;
    char* Bs = As + 8192;
#pragma unroll
    for (int i = 0; i < 2; ++i) {
      int r = ((i << 2) + wv) * 8 + (ln >> 3);
      int sc = (ln & 7) ^ (r & 7);
      gload16((const char*)(A + (size_t)(m0 + r) * K + k0) + (sc << 4),
              As + (((i << 2) + wv) << 10));
      gload16((const char*)(W + (size_t)(n0 + r) * K + k0) + (sc << 4),
              Bs + (((i << 2) + wv) << 10));
    }
  };

  stage(0, 0);
  __syncthreads();
  for (int kb = 0; kb < nkb; ++kb) {
    int buf = kb & 1;
    if (kb + 1 < nkb) stage(kb + 1, buf ^ 1);
    const char* As = smem + buf * 16384;
    const char* Bs = As + 8192;
#pragma unroll
    for (int ks = 0; ks < 2; ++ks) {
      const int kc = (ks << 2) + (ln >> 4);
      auto ld = [&](const char* base, int row) -> bf16x8 {
        return *(const bf16x8*)(base + row * 128 + ((kc ^ (row & 7)) << 4));
      };
      bf16x8 A0 = ld(As, wm + (ln & 15));
      bf16x8 A1 = ld(As, wm + 16 + (ln & 15));
      bf16x8 B0 = ld(Bs, wn + (ln & 15));
      bf16x8 B1 = ld(Bs, wn + 16 + (ln & 15));
      acc00 = MFMA16(A0, B0, acc00);
      acc01 = MFMA16(A0, B1, acc01);
      acc10 = MFMA16(A1, B0, acc10);
      acc11 = MFMA16(A1, B1, acc11);
    }
    __syncthreads();
  }

#pragma unroll
  for (int mi = 0; mi < 2; ++mi)
#pragma unroll
    for (int ni = 0; ni < 2; ++ni) {
      f32x4 a = (mi == 0) ? (ni == 0 ? acc00 : acc01) : (ni == 0 ? acc10 : acc11);
#pragma unroll
      for (int r = 0; r < 4; ++r) {
        int m = m0 + wm + mi * 16 + ((ln >> 4) << 2) + r;
        int n = n0 + wn + ni * 16 + (ln & 15);
        float v = a[r];
        if constexpr (EP == 0) {
          o1[(size_t)m * Nn + n] = __float2bfloat16(v);
        } else if constexpr (EP == 1) {
          v = tanhf(v + bias[n]);
          int q = n >> 10, hh = n & 1023;
          int sseg = m >> 8, b = m & 255;
          size_t pidx = (size_t)sseg * 262144 +
              ((size_t)(b >> 5) * 128 + (hh >> 3)) * 256 + (b & 31) * 8 + (hh & 7);
          size_t idx = (size_t)m * 1024 + hh;
          if (q == 0)      o1[pidx] = __float2bfloat16(v);
          else if (q == 1) o2[pidx] = __float2bfloat16(v);
          else if (q == 2) f1[idx] = v;
          else             f2[idx] = v;
        } else if constexpr (EP == 2) {
          f1[(size_t)m * 4096 + n] = v + bias[n];
        } else {
          int b = m & 255, g = (m >> 8) + gt_base;
          f1[(size_t)b * 131072 + (size_t)g * 512 + n] = v + bias[n];
        }
      }
    }
}

// ------------------------- small prep kernels ------------------------------
__global__ void k_conv(const float* __restrict__ s, bf16* __restrict__ d, int n) {
  int i = blockIdx.x * 256 + threadIdx.x;
  if (i < n) d[i] = __float2bfloat16(s[i]);
}
__global__ void k_trans_wout(const float* __restrict__ s, bf16* __restrict__ d) {
  int i = blockIdx.x * 256 + threadIdx.x;
  int l = i >> 9, j = i & 511;
  d[i] = __float2bfloat16(s[(size_t)j * 1024 + l]);
}
// gate-interleaved reorder, ROW-MAJOR: dst row n'=4h+q <- src row q*1024+h
__global__ void k_reorder_g(const float* __restrict__ s, bf16* __restrict__ d) {
  int i = blockIdx.x * 256 + threadIdx.x;  // 4096*1024
  int np = i >> 10, kx = i & 1023;
  int hh = np >> 2, q = np & 3;
  d[i] = __float2bfloat16(s[(size_t)(q * 1024 + hh) * 1024 + kx]);
}
// row-major 512-wide slice of W_ih1
__global__ void k_reorder_c(const float* __restrict__ s, bf16* __restrict__ d, int coloff) {
  int i = blockIdx.x * 256 + threadIdx.x;
  int np = i >> 9, kx = i & 511;
  int hh = np >> 2, q = np & 3;
  d[i] = __float2bfloat16(s[(size_t)(q * 1024 + hh) * 1024 + coloff + kx]);
}
__global__ void k_bias(const float* __restrict__ bih1, const float* __restrict__ bhh1,
                       const float* __restrict__ bih2, const float* __restrict__ bhh2,
                       const float* __restrict__ bo,   const float* __restrict__ Wih1,
                       float* __restrict__ b1r, float* __restrict__ b2r,
                       float* __restrict__ bfr) {
  int n = blockIdx.x * 256 + threadIdx.x;
  int hh = n >> 2, q = n & 3, r = q * 1024 + hh;
  const float* wrow = Wih1 + (size_t)r * 1024 + 512;
  float acc = 0.f;
  for (int j = 0; j < 512; ++j) acc += bo[j] * wrow[j];
  bfr[n] = acc;
  b1r[n] = bih1[r] + bhh1[r] + acc;
  b2r[n] = bih2[r] + bhh2[r];
}
__global__ void k_ratio(float* __restrict__ dst, const int* __restrict__ ep,
                        const int* __restrict__ kv) {
  float kf = (float)kv[0];
  dst[0] = kf / (kf + __expf((float)ep[0] / kf));
}

// ---------------------------------------------------------------------------
extern "C" void kernel_launch(void* const* d_in, const int* in_sizes, int n_in,
                              void* d_out, int out_size, void* d_ws, size_t ws_size,
                              hipStream_t stream) {
  (void)in_sizes; (void)n_in; (void)ws_size;
  const float* in_c     = (const float*)d_in[0];
  const float* in_Winit = (const float*)d_in[1];
  const float* in_binit = (const float*)d_in[2];
  const float* in_Wih1  = (const float*)d_in[3];
  const float* in_Whh1  = (const float*)d_in[4];
  const float* in_bih1  = (const float*)d_in[5];
  const float* in_bhh1  = (const float*)d_in[6];
  const float* in_Wih2  = (const float*)d_in[7];
  const float* in_Whh2  = (const float*)d_in[8];
  const float* in_bih2  = (const float*)d_in[9];
  const float* in_bhh2  = (const float*)d_in[10];
  const float* in_Wout  = (const float*)d_in[11];
  const float* in_bout  = (const float*)d_in[12];
  const int*   in_epoch = (const int*)d_in[14];
  const int*   in_k     = (const int*)d_in[15];
  float* out = (float*)d_out;

  char* p = (char*)d_ws;
  auto alloc = [&](size_t bytes) { char* q = p; p += (bytes + 255) & ~(size_t)255; return q; };
  bf16* wHH1  = (bf16*)alloc(4096ull * 1024 * 2);   // row-major gate-interleaved
  bf16* wFOLD = (bf16*)alloc(4096ull * 1024 * 2);   // row-major (via EP0)
  bf16* wIH2  = (bf16*)alloc(4096ull * 1024 * 2);   // row-major
  bf16* wHH2  = (bf16*)alloc(4096ull * 1024 * 2);   // row-major
  bf16* wOUT  = (bf16*)alloc(512ull * 1024 * 2);    // row-major
  bf16* wOUTT = (bf16*)alloc(1024ull * 512 * 2);    // row-major
  bf16* wINIT = (bf16*)alloc(4096ull * 512 * 2);    // row-major
  bf16* wIH1C = (bf16*)alloc(4096ull * 512 * 2);    // row-major
  bf16* wPREV = (bf16*)alloc(4096ull * 512 * 2);    // row-major
  bf16* cbf   = (bf16*)alloc(4096ull * 512 * 2);
  float* b1r  = (float*)alloc(4096 * 4);
  float* b2r  = (float*)alloc(4096 * 4);
  float* bfr  = (float*)alloc(4096 * 4);
  bf16* h1i   = (bf16*)alloc(16ull * 256 * 1024 * 2);   // permuted per segment
  bf16* h2i   = (bf16*)alloc(16ull * 256 * 1024 * 2);   // permuted per segment
  float* c1i  = (float*)alloc(16ull * 256 * 1024 * 4);  // row-major
  float* c2i  = (float*)alloc(16ull * 256 * 1024 * 4);  // row-major
  float* PE1  = (float*)alloc(16ull * 256 * 4096 * 4);
  bf16* h1p[2]; bf16* h2p[2]; float* c1b[2]; float* c2b[2];
  for (int i = 0; i < 2; ++i) {
    h1p[i] = (bf16*)alloc(256ull * 1024 * 2);   // permuted
    h2p[i] = (bf16*)alloc(256ull * 1024 * 2);   // permuted
    c1b[i] = (float*)alloc(256ull * 1024 * 4);
    c2b[i] = (float*)alloc(256ull * 1024 * 4);
  }
  bf16* hist = (bf16*)alloc(256ull * 256 * 1024 * 2);   // row-major

  // ---- prep ----
  k_conv<<<8192, 256, 0, stream>>>(in_c, cbf, 2097152);
  k_conv<<<2048, 256, 0, stream>>>(in_Wout, wOUT, 524288);
  k_conv<<<8192, 256, 0, stream>>>(in_Winit, wINIT, 2097152);
  k_trans_wout<<<2048, 256, 0, stream>>>(in_Wout, wOUTT);
  k_reorder_g<<<16384, 256, 0, stream>>>(in_Whh1, wHH1);
  k_reorder_g<<<16384, 256, 0, stream>>>(in_Wih2, wIH2);
  k_reorder_g<<<16384, 256, 0, stream>>>(in_Whh2, wHH2);
  k_reorder_c<<<8192, 256, 0, stream>>>(in_Wih1, wIH1C, 0);
  k_reorder_c<<<8192, 256, 0, stream>>>(in_Wih1, wPREV, 512);
  k_bias<<<16, 256, 0, stream>>>(in_bih1, in_bhh1, in_bih2, in_bhh2, in_bout,
                                 in_Wih1, b1r, b2r, bfr);
  // W_fold (row-major) = Wp_r @ W_out   (M=4096,N=1024,K=512)
  gemm_ep<0><<<dim3(16, 64), 256, 0, stream>>>(wPREV, wOUTT, 512, nullptr,
                                               nullptr, nullptr, wFOLD, nullptr, 0);
  // init states: tanh(c @ W_init.T + b_init) -> h1i/h2i permuted, c1i/c2i f32
  gemm_ep<1><<<dim3(64, 64), 256, 0, stream>>>(cbf, wINIT, 512, in_binit,
                                               c1i, c2i, h1i, h2i, 0);
  // PE1[s][b][n'] = embed @ W_ih1_cond.T + (b_ih1+b_hh1+b_fold)
  gemm_ep<2><<<dim3(64, 64), 256, 0, stream>>>(cbf, wIH1C, 512, b1r,
                                               PE1, nullptr, nullptr, nullptr, 0);

  // ---- recurrence: 16 segments x 16 steps, 2 GEMM launches each ----
  const size_t S = 256ull * 1024;
  for (int s = 0; s < 16; ++s) {
    for (int t = 0; t < 16; ++t) {
      int gt = s * 16 + t;
      int cur = gt & 1, prv = cur ^ 1;
      // prev carries ACROSS segment boundaries: layer-1's folded operand is
      // always the previous step's h2 (h2p[prv]), even at t==0.
      const bf16* h2prev = (gt == 0) ? nullptr : h2p[prv];
      // layer 1: g1 = PE1[s] + h1@W_hh1' + h2prev@W_fold'  (-b_fold at gt==0)
      rnn_step<<<256, 512, 0, stream>>>(
          (t == 0) ? h1i + (size_t)s * S : h1p[prv], h2prev,
          wHH1, wFOLD,
          PE1 + (size_t)s * 1048576, nullptr, (gt == 0) ? bfr : nullptr,
          (t == 0) ? c1i + (size_t)s * S : c1b[prv], c1b[cur],
          h1p[cur], nullptr);
      // layer 2: g2 = h1new@W_ih2' + h2@W_hh2' + b2   (h2 state IS re-init at t==0)
      rnn_step<<<256, 512, 0, stream>>>(
          h1p[cur],
          (t == 0) ? h2i + (size_t)s * S : h2p[prv],
          wIH2, wHH2, nullptr, b2r, nullptr,
          (t == 0) ? c2i + (size_t)s * S : c2b[prv], c2b[cur],
          h2p[cur], hist + (size_t)gt * S);
    }
  }

  // ---- outputs: one big GEMM over the row-major h2 history ----
  gemm_ep<3><<<dim3(8, 1024), 256, 0, stream>>>(hist, wOUT, 1024, in_bout,
                                                out, nullptr, nullptr, nullptr, 0);
  k_ratio<<<1, 1, 0, stream>>>(out + (out_size - 1), in_epoch, in_k);
}

// Round 10
// 6616.596 us; speedup vs baseline: 3.1071x; 1.0099x over previous
//
#include <hip/hip_runtime.h>
#include <hip/hip_bf16.h>

using bf16 = __hip_bfloat16;
typedef __attribute__((ext_vector_type(8))) short bf16x8;
typedef __attribute__((ext_vector_type(4))) float f32x4;

__device__ __forceinline__ void gload16(const void* g, void* l) {
  __builtin_amdgcn_global_load_lds((const __attribute__((address_space(1))) void*)g,
                                   (__attribute__((address_space(3))) void*)l, 16, 0, 0);
}

__device__ __forceinline__ float sigm(float x) { return 1.0f / (1.0f + __expf(-x)); }
// overflow-safe fast tanh
__device__ __forceinline__ float ftanh(float x) {
  float e = __expf(2.0f * fabsf(x));
  return copysignf(1.0f - 2.0f / (e + 1.0f), x);
}

#define MFMA16(a, b, c) __builtin_amdgcn_mfma_f32_16x16x32_bf16(a, b, c, 0, 0, 0)

// Fragment-major ("permuted") layout for a [M][1024] bf16 matrix:
// elem(m,k) -> ((m>>5)*128 + (k>>3))*256 + (m&31)*8 + (k&7)
// A wave's 16x16x32 A-fragment is then one contiguous 1KB burst.

// ---------------------------------------------------------------------------
// Recurrent step GEMM: g[256,4096] = pe + a1@w1.T + a2@w2.T (+bias -bsub),
// fused LSTM-gate epilogue (weights gate-interleaved: col n = 4*h + q).
// 1024 threads = 16 waves = 4 K-groups x 4 waves (4 waves/SIMD occupancy).
// Group g: operand (g<2 ? a1,w1 : a2,w2), k-base (g&1)*512; K=512 = 16 kb.
// Dataflow: B (weights) via global_load_lds into an 8-slot/group LDS ring;
// A (h-states, permuted) direct global->VGPR. LDS traffic halved vs R5.
// Counted-vmcnt pipeline: A-cover 3 iters, B-cover 6; 16 barriers/GEMM.
// grid 256 linear (XCD-decoded), block 1024.
// ---------------------------------------------------------------------------
__global__ __launch_bounds__(1024, 4) void rnn_step(
    const bf16* __restrict__ a1, const bf16* __restrict__ a2,
    const bf16* __restrict__ w1, const bf16* __restrict__ w2,
    const float* __restrict__ pe, const float* __restrict__ bias,
    const float* __restrict__ bsub,
    const float* __restrict__ c_in, float* __restrict__ c_out,
    bf16* __restrict__ hp_out, bf16* __restrict__ hrow_out)
{
  __shared__ __attribute__((aligned(128))) char smem[131072];
  const int tid = threadIdx.x;
  const int wv = tid >> 6, ln = tid & 63;
  const int grp = wv >> 2, wg = wv & 3;
  // XCD-aware decode: blocks sharing a B-panel (same nt) land on one XCD.
  const int bid = blockIdx.x;
  const int nt = ((bid & 7) << 3) | ((bid >> 3) & 7);
  const int mt = bid >> 6;
  const int m0 = mt << 6, n0 = nt << 6;
  const int wm = (wg >> 1) << 5, wn = (wg & 1) << 5;
  const bool use2 = (a2 != nullptr);

  const bf16* asrc = (!use2 || grp < 2) ? a1 : a2;
  const bf16* wsrc = (!use2 || grp < 2) ? w1 : w2;
  const int kbase = (grp & 1) << 9;  // element offset within the K=1024 operand

  char* gbase = smem + (grp << 15);  // 32KB/group: 8 slots x 4KB (B only)

  // ---- B staging (row-major weights, row stride 2048B) ----
  const int srow = (wg << 4) + (ln >> 2);          // n-row this lane fills
  const int skc  = (ln & 3) ^ ((srow >> 1) & 3);   // pre-swizzled 16B chunk
  const char* bsrcB = (const char*)wsrc + (size_t)(n0 + srow) * 2048
                      + (kbase << 1) + (skc << 4);

  // ---- A direct loads (fragment-major permuted) ----
  const int r16 = ln & 15, kc4 = ln >> 4;
  const int mgA = m0 + wm + r16;
  const char* pa = (const char*)asrc +
      ((size_t)(mgA >> 5) * 128 + (kbase >> 3) + kc4) * 512 + (size_t)(mgA & 31) * 16;

  // ---- B read offsets (swizzled, 4KB slot = 64 rows x 64B) ----
  const int br0 = wn + r16, br1 = br0 + 16;
  const int boff0 = br0 * 64 + ((kc4 ^ ((br0 >> 1) & 3)) << 4);
  const int boff1 = br1 * 64 + ((kc4 ^ ((br1 >> 1) & 3)) << 4);

  f32x4 acc00{}, acc01{}, acc10{}, acc11{};
  bf16x8 fa0[4], fa1[4];

#define STAGEB(kb) gload16(bsrcB + (kb) * 64, gbase + (((kb) & 7) << 12) + (wg << 10))
#define LOADA(kb) do {                                                  \
    fa0[(kb) & 3] = *(const bf16x8*)(pa + (size_t)(kb) * 2048);         \
    fa1[(kb) & 3] = *(const bf16x8*)(pa + (size_t)(kb) * 2048 + 256);   \
  } while (0)
#define WAITN(n) asm volatile("s_waitcnt vmcnt(" #n ")" ::: "memory")
#define KSTEP(kb, WN, DOB, DOA) do {                                    \
    WAITN(WN);                                                          \
    __builtin_amdgcn_s_barrier();                                       \
    asm volatile("" ::: "memory");                                      \
    if (DOB) STAGEB((kb) + 6);                                          \
    if (DOA) LOADA((kb) + 3);                                           \
    __builtin_amdgcn_s_setprio(1);                                      \
    {                                                                   \
      const char* sb = gbase + (((kb) & 7) << 12);                      \
      bf16x8 b0 = *(const bf16x8*)(sb + boff0);                         \
      bf16x8 b1 = *(const bf16x8*)(sb + boff1);                         \
      acc00 = MFMA16(fa0[(kb) & 3], b0, acc00);                         \
      acc01 = MFMA16(fa0[(kb) & 3], b1, acc01);                         \
      acc10 = MFMA16(fa1[(kb) & 3], b0, acc10);                         \
      acc11 = MFMA16(fa1[(kb) & 3], b1, acc11);                         \
    }                                                                   \
    __builtin_amdgcn_s_setprio(0);                                      \
  } while (0)

  // prologue queue: B0 A0 B1 A1 B2 A2 B3 B4 B5 (12 vmcnt ops; LOADA = 2)
  STAGEB(0); LOADA(0);
  STAGEB(1); LOADA(1);
  STAGEB(2); LOADA(2);
  STAGEB(3); STAGEB(4); STAGEB(5);
  // waits derived by queue induction (need B(kb)+A(kb) done at each step)
  KSTEP(0, 9, 1, 1);
  KSTEP(1, 8, 1, 1);
  KSTEP(2, 9, 1, 1);
  KSTEP(3, 6, 1, 1);
  KSTEP(4, 6, 1, 1);
  KSTEP(5, 6, 1, 1);
  KSTEP(6, 6, 1, 1);
  KSTEP(7, 6, 1, 1);
  KSTEP(8, 6, 1, 1);
  KSTEP(9, 6, 1, 1);
  KSTEP(10, 6, 0, 1);
  KSTEP(11, 5, 0, 1);
  KSTEP(12, 4, 0, 1);
  KSTEP(13, 4, 0, 0);
  KSTEP(14, 2, 0, 0);
  KSTEP(15, 0, 0, 0);
#undef KSTEP
#undef WAITN
#undef LOADA
#undef STAGEB

  // ---- epilogue: merge 4 group-partials, LSTM nonlinearity ----
  __syncthreads();  // all ring reads done before gs overwrites smem
  float* gs = (float*)smem;  // [4][64][68]
#pragma unroll
  for (int mi = 0; mi < 2; ++mi)
#pragma unroll
    for (int ni = 0; ni < 2; ++ni) {
      f32x4 a = (mi == 0) ? (ni == 0 ? acc00 : acc01) : (ni == 0 ? acc10 : acc11);
#pragma unroll
      for (int r = 0; r < 4; ++r) {
        int row = wm + mi * 16 + ((ln >> 4) << 2) + r;
        int col = wn + ni * 16 + (ln & 15);
        gs[grp * 4352 + row * 68 + col] = a[r];
      }
    }
  __syncthreads();

  const int m = tid >> 4, h = tid & 15;   // 64 x 16 = 1024 threads, 1 elem each
  const int gm = m0 + m, hg = (nt << 4) + h;
  float4 v0 = *(const float4*)(gs + m * 68 + (h << 2));
  float4 v1 = *(const float4*)(gs + 4352 + m * 68 + (h << 2));
  float g0 = v0.x + v1.x, g1 = v0.y + v1.y, g2 = v0.z + v1.z, g3 = v0.w + v1.w;
  if (use2) {
    float4 v2 = *(const float4*)(gs + 2 * 4352 + m * 68 + (h << 2));
    float4 v3 = *(const float4*)(gs + 3 * 4352 + m * 68 + (h << 2));
    g0 += v2.x + v3.x; g1 += v2.y + v3.y; g2 += v2.z + v3.z; g3 += v2.w + v3.w;
  }
  int nb = n0 + (h << 2);
  if (pe) { float4 pv = *(const float4*)(pe + (size_t)gm * 4096 + nb);
            g0 += pv.x; g1 += pv.y; g2 += pv.z; g3 += pv.w; }
  if (bias){ float4 bv = *(const float4*)(bias + nb);
            g0 += bv.x; g1 += bv.y; g2 += bv.z; g3 += bv.w; }
  if (bsub){ float4 sv = *(const float4*)(bsub + nb);
            g0 -= sv.x; g1 -= sv.y; g2 -= sv.z; g3 -= sv.w; }
  float ig = sigm(g0), fg = sigm(g1), gg = ftanh(g2), og = sigm(g3);
  size_t idx = (size_t)gm * 1024 + hg;
  float cn = fg * c_in[idx] + ig * gg;
  c_out[idx] = cn;
  bf16 hv = __float2bfloat16(og * ftanh(cn));
  hp_out[((size_t)(gm >> 5) * 128 + (hg >> 3)) * 256 + (gm & 31) * 8 + (hg & 7)] = hv;
  if (hrow_out) hrow_out[idx] = hv;
}

// ---------------------------------------------------------------------------
// Generic 64x64-tile bf16 GEMM C = A @ W.T with epilogues:
// EP0: store bf16 row-major to o1[M][N]  (W_fold build -- staged as B later)
// EP1: tanh(v+bias[n]); h1i/h2i written PERMUTED per segment; c1i/c2i f32
// EP2: f1[m*4096+n] = v + bias[n]        (PE build)
// EP3: f1[b*131072 + gt*512 + n] = v + bias[n], m = gt_local*256+b (outputs)
// ---------------------------------------------------------------------------
template <int EP>
__global__ __launch_bounds__(256) void gemm_ep(
    const bf16* __restrict__ A, const bf16* __restrict__ W, int K,
    const float* __restrict__ bias,
    float* __restrict__ f1, float* __restrict__ f2,
    bf16* __restrict__ o1, bf16* __restrict__ o2, int gt_base)
{
  __shared__ __attribute__((aligned(128))) char smem[32768];
  const int tid = threadIdx.x;
  const int wv = tid >> 6, ln = tid & 63;
  const int n0 = blockIdx.x << 6;
  const int m0 = blockIdx.y << 6;
  const int Nn = (int)(gridDim.x << 6);
  const int wm = (wv >> 1) << 5, wn = (wv & 1) << 5;
  const int nkb = K >> 6;

  f32x4 acc00{}, acc01{}, acc10{}, acc11{};

  auto stage = [&](int kb, int buf) {
    int k0 = kb << 6;
    char* As = smem + buf * 16384;
    char* Bs = As + 8192;
#pragma unroll
    for (int i = 0; i < 2; ++i) {
      int r = ((i << 2) + wv) * 8 + (ln >> 3);
      int sc = (ln & 7) ^ (r & 7);
      gload16((const char*)(A + (size_t)(m0 + r) * K + k0) + (sc << 4),
              As + (((i << 2) + wv) << 10));
      gload16((const char*)(W + (size_t)(n0 + r) * K + k0) + (sc << 4),
              Bs + (((i << 2) + wv) << 10));
    }
  };

  stage(0, 0);
  __syncthreads();
  for (int kb = 0; kb < nkb; ++kb) {
    int buf = kb & 1;
    if (kb + 1 < nkb) stage(kb + 1, buf ^ 1);
    const char* As = smem + buf * 16384;
    const char* Bs = As + 8192;
#pragma unroll
    for (int ks = 0; ks < 2; ++ks) {
      const int kc = (ks << 2) + (ln >> 4);
      auto ld = [&](const char* base, int row) -> bf16x8 {
        return *(const bf16x8*)(base + row * 128 + ((kc ^ (row & 7)) << 4));
      };
      bf16x8 A0 = ld(As, wm + (ln & 15));
      bf16x8 A1 = ld(As, wm + 16 + (ln & 15));
      bf16x8 B0 = ld(Bs, wn + (ln & 15));
      bf16x8 B1 = ld(Bs, wn + 16 + (ln & 15));
      acc00 = MFMA16(A0, B0, acc00);
      acc01 = MFMA16(A0, B1, acc01);
      acc10 = MFMA16(A1, B0, acc10);
      acc11 = MFMA16(A1, B1, acc11);
    }
    __syncthreads();
  }

#pragma unroll
  for (int mi = 0; mi < 2; ++mi)
#pragma unroll
    for (int ni = 0; ni < 2; ++ni) {
      f32x4 a = (mi == 0) ? (ni == 0 ? acc00 : acc01) : (ni == 0 ? acc10 : acc11);
#pragma unroll
      for (int r = 0; r < 4; ++r) {
        int m = m0 + wm + mi * 16 + ((ln >> 4) << 2) + r;
        int n = n0 + wn + ni * 16 + (ln & 15);
        float v = a[r];
        if constexpr (EP == 0) {
          o1[(size_t)m * Nn + n] = __float2bfloat16(v);
        } else if constexpr (EP == 1) {
          v = tanhf(v + bias[n]);
          int q = n >> 10, hh = n & 1023;
          int sseg = m >> 8, b = m & 255;
          size_t pidx = (size_t)sseg * 262144 +
              ((size_t)(b >> 5) * 128 + (hh >> 3)) * 256 + (b & 31) * 8 + (hh & 7);
          size_t idx = (size_t)m * 1024 + hh;
          if (q == 0)      o1[pidx] = __float2bfloat16(v);
          else if (q == 1) o2[pidx] = __float2bfloat16(v);
          else if (q == 2) f1[idx] = v;
          else             f2[idx] = v;
        } else if constexpr (EP == 2) {
          f1[(size_t)m * 4096 + n] = v + bias[n];
        } else {
          int b = m & 255, g = (m >> 8) + gt_base;
          f1[(size_t)b * 131072 + (size_t)g * 512 + n] = v + bias[n];
        }
      }
    }
}

// ------------------------- small prep kernels ------------------------------
__global__ void k_conv(const float* __restrict__ s, bf16* __restrict__ d, int n) {
  int i = blockIdx.x * 256 + threadIdx.x;
  if (i < n) d[i] = __float2bfloat16(s[i]);
}
__global__ void k_trans_wout(const float* __restrict__ s, bf16* __restrict__ d) {
  int i = blockIdx.x * 256 + threadIdx.x;
  int l = i >> 9, j = i & 511;
  d[i] = __float2bfloat16(s[(size_t)j * 1024 + l]);
}
// gate-interleaved reorder, ROW-MAJOR: dst row n'=4h+q <- src row q*1024+h
__global__ void k_reorder_g(const float* __restrict__ s, bf16* __restrict__ d) {
  int i = blockIdx.x * 256 + threadIdx.x;  // 4096*1024
  int np = i >> 10, kx = i & 1023;
  int hh = np >> 2, q = np & 3;
  d[i] = __float2bfloat16(s[(size_t)(q * 1024 + hh) * 1024 + kx]);
}
// row-major 512-wide slice of W_ih1
__global__ void k_reorder_c(const float* __restrict__ s, bf16* __restrict__ d, int coloff) {
  int i = blockIdx.x * 256 + threadIdx.x;
  int np = i >> 9, kx = i & 511;
  int hh = np >> 2, q = np & 3;
  d[i] = __float2bfloat16(s[(size_t)(q * 1024 + hh) * 1024 + coloff + kx]);
}
__global__ void k_bias(const float* __restrict__ bih1, const float* __restrict__ bhh1,
                       const float* __restrict__ bih2, const float* __restrict__ bhh2,
                       const float* __restrict__ bo,   const float* __restrict__ Wih1,
                       float* __restrict__ b1r, float* __restrict__ b2r,
                       float* __restrict__ bfr) {
  int n = blockIdx.x * 256 + threadIdx.x;
  int hh = n >> 2, q = n & 3, r = q * 1024 + hh;
  const float* wrow = Wih1 + (size_t)r * 1024 + 512;
  float acc = 0.f;
  for (int j = 0; j < 512; ++j) acc += bo[j] * wrow[j];
  bfr[n] = acc;
  b1r[n] = bih1[r] + bhh1[r] + acc;
  b2r[n] = bih2[r] + bhh2[r];
}
__global__ void k_ratio(float* __restrict__ dst, const int* __restrict__ ep,
                        const int* __restrict__ kv) {
  float kf = (float)kv[0];
  dst[0] = kf / (kf + __expf((float)ep[0] / kf));
}

// ---------------------------------------------------------------------------
extern "C" void kernel_launch(void* const* d_in, const int* in_sizes, int n_in,
                              void* d_out, int out_size, void* d_ws, size_t ws_size,
                              hipStream_t stream) {
  (void)in_sizes; (void)n_in; (void)ws_size;
  const float* in_c     = (const float*)d_in[0];
  const float* in_Winit = (const float*)d_in[1];
  const float* in_binit = (const float*)d_in[2];
  const float* in_Wih1  = (const float*)d_in[3];
  const float* in_Whh1  = (const float*)d_in[4];
  const float* in_bih1  = (const float*)d_in[5];
  const float* in_bhh1  = (const float*)d_in[6];
  const float* in_Wih2  = (const float*)d_in[7];
  const float* in_Whh2  = (const float*)d_in[8];
  const float* in_bih2  = (const float*)d_in[9];
  const float* in_bhh2  = (const float*)d_in[10];
  const float* in_Wout  = (const float*)d_in[11];
  const float* in_bout  = (const float*)d_in[12];
  const int*   in_epoch = (const int*)d_in[14];
  const int*   in_k     = (const int*)d_in[15];
  float* out = (float*)d_out;

  char* p = (char*)d_ws;
  auto alloc = [&](size_t bytes) { char* q = p; p += (bytes + 255) & ~(size_t)255; return q; };
  bf16* wHH1  = (bf16*)alloc(4096ull * 1024 * 2);   // row-major gate-interleaved
  bf16* wFOLD = (bf16*)alloc(4096ull * 1024 * 2);   // row-major (via EP0)
  bf16* wIH2  = (bf16*)alloc(4096ull * 1024 * 2);   // row-major
  bf16* wHH2  = (bf16*)alloc(4096ull * 1024 * 2);   // row-major
  bf16* wOUT  = (bf16*)alloc(512ull * 1024 * 2);    // row-major
  bf16* wOUTT = (bf16*)alloc(1024ull * 512 * 2);    // row-major
  bf16* wINIT = (bf16*)alloc(4096ull * 512 * 2);    // row-major
  bf16* wIH1C = (bf16*)alloc(4096ull * 512 * 2);    // row-major
  bf16* wPREV = (bf16*)alloc(4096ull * 512 * 2);    // row-major
  bf16* cbf   = (bf16*)alloc(4096ull * 512 * 2);
  float* b1r  = (float*)alloc(4096 * 4);
  float* b2r  = (float*)alloc(4096 * 4);
  float* bfr  = (float*)alloc(4096 * 4);
  bf16* h1i   = (bf16*)alloc(16ull * 256 * 1024 * 2);   // permuted per segment
  bf16* h2i   = (bf16*)alloc(16ull * 256 * 1024 * 2);   // permuted per segment
  float* c1i  = (float*)alloc(16ull * 256 * 1024 * 4);  // row-major
  float* c2i  = (float*)alloc(16ull * 256 * 1024 * 4);  // row-major
  float* PE1  = (float*)alloc(16ull * 256 * 4096 * 4);
  bf16* h1p[2]; bf16* h2p[2]; float* c1b[2]; float* c2b[2];
  for (int i = 0; i < 2; ++i) {
    h1p[i] = (bf16*)alloc(256ull * 1024 * 2);   // permuted
    h2p[i] = (bf16*)alloc(256ull * 1024 * 2);   // permuted
    c1b[i] = (float*)alloc(256ull * 1024 * 4);
    c2b[i] = (float*)alloc(256ull * 1024 * 4);
  }
  bf16* hist = (bf16*)alloc(256ull * 256 * 1024 * 2);   // row-major

  // ---- prep ----
  k_conv<<<8192, 256, 0, stream>>>(in_c, cbf, 2097152);
  k_conv<<<2048, 256, 0, stream>>>(in_Wout, wOUT, 524288);
  k_conv<<<8192, 256, 0, stream>>>(in_Winit, wINIT, 2097152);
  k_trans_wout<<<2048, 256, 0, stream>>>(in_Wout, wOUTT);
  k_reorder_g<<<16384, 256, 0, stream>>>(in_Whh1, wHH1);
  k_reorder_g<<<16384, 256, 0, stream>>>(in_Wih2, wIH2);
  k_reorder_g<<<16384, 256, 0, stream>>>(in_Whh2, wHH2);
  k_reorder_c<<<8192, 256, 0, stream>>>(in_Wih1, wIH1C, 0);
  k_reorder_c<<<8192, 256, 0, stream>>>(in_Wih1, wPREV, 512);
  k_bias<<<16, 256, 0, stream>>>(in_bih1, in_bhh1, in_bih2, in_bhh2, in_bout,
                                 in_Wih1, b1r, b2r, bfr);
  // W_fold (row-major) = Wp_r @ W_out   (M=4096,N=1024,K=512)
  gemm_ep<0><<<dim3(16, 64), 256, 0, stream>>>(wPREV, wOUTT, 512, nullptr,
                                               nullptr, nullptr, wFOLD, nullptr, 0);
  // init states: tanh(c @ W_init.T + b_init) -> h1i/h2i permuted, c1i/c2i f32
  gemm_ep<1><<<dim3(64, 64), 256, 0, stream>>>(cbf, wINIT, 512, in_binit,
                                               c1i, c2i, h1i, h2i, 0);
  // PE1[s][b][n'] = embed @ W_ih1_cond.T + (b_ih1+b_hh1+b_fold)
  gemm_ep<2><<<dim3(64, 64), 256, 0, stream>>>(cbf, wIH1C, 512, b1r,
                                               PE1, nullptr, nullptr, nullptr, 0);

  // ---- recurrence: 16 segments x 16 steps, 2 GEMM launches each ----
  const size_t S = 256ull * 1024;
  for (int s = 0; s < 16; ++s) {
    for (int t = 0; t < 16; ++t) {
      int gt = s * 16 + t;
      int cur = gt & 1, prv = cur ^ 1;
      // prev carries ACROSS segment boundaries: layer-1's folded operand is
      // always the previous step's h2 (h2p[prv]), even at t==0.
      const bf16* h2prev = (gt == 0) ? nullptr : h2p[prv];
      // layer 1: g1 = PE1[s] + h1@W_hh1' + h2prev@W_fold'  (-b_fold at gt==0)
      rnn_step<<<256, 1024, 0, stream>>>(
          (t == 0) ? h1i + (size_t)s * S : h1p[prv], h2prev,
          wHH1, wFOLD,
          PE1 + (size_t)s * 1048576, nullptr, (gt == 0) ? bfr : nullptr,
          (t == 0) ? c1i + (size_t)s * S : c1b[prv], c1b[cur],
          h1p[cur], nullptr);
      // layer 2: g2 = h1new@W_ih2' + h2@W_hh2' + b2   (h2 state IS re-init at t==0)
      rnn_step<<<256, 1024, 0, stream>>>(
          h1p[cur],
          (t == 0) ? h2i + (size_t)s * S : h2p[prv],
          wIH2, wHH2, nullptr, b2r, nullptr,
          (t == 0) ? c2i + (size_t)s * S : c2b[prv], c2b[cur],
          h2p[cur], hist + (size_t)gt * S);
    }
  }

  // ---- outputs: one big GEMM over the row-major h2 history ----
  gemm_ep<3><<<dim3(8, 1024), 256, 0, stream>>>(hist, wOUT, 1024, in_bout,
                                                out, nullptr, nullptr, nullptr, 0);
  k_ratio<<<1, 1, 0, stream>>>(out + (out_size - 1), in_epoch, in_k);
}